// Round 1
// 488.249 us; speedup vs baseline: 1.0012x; 1.0012x over previous
//
#include <hip/hip_runtime.h>
#include <math.h>

// Problem constants (fixed by the reference: B=16, C=256, H=W=128, K=7)
#define HW      128
#define PLANE   16384                 // 128*128
#define CHS     256
#define BATCH   16
#define CSTRIDE 16384                 // plane stride in floats
#define BSTRIDE (256 * 16384)         // batch stride in floats = 4194304
#define CB      4                     // batches per chunk (64 MiB x-chunk)
#define NCHUNK  (BATCH / CB)          // 4 chunks
// Pipeline: R(c0) | G(c0)||R(c1) | G(c1)||R(c2) | G(c2)||R(c3) | G(c3)
// Middle stages mix the HBM read stream (reduce of next chunk) with the HBM
// write stream (gate of current chunk); L3 pressure per stage is
// 64 MiB (re-read set) + 64 MiB (incoming) << 256 MiB L3. out is NT (bypass).

typedef float vf4 __attribute__((ext_vector_type(4)));   // for __builtin_nontemporal_store

// ---------------------------------------------------------------------------
// Reduce body: channel-wise max + mean over C=256.
// One "reduce block unit" rb in [0, CB*128): 32 float4 spatial chunks
// (sc = tid & 31) x 8 channel groups (cg = tid >> 5, 32 channels each).
// ---------------------------------------------------------------------------
__device__ __forceinline__ void reduce_body(
    const float* __restrict__ x, float* __restrict__ pmax, float* __restrict__ pavg,
    int b0, int rb)
{
    __shared__ float4 smax[256];
    __shared__ float4 ssum[256];

    const int tid = threadIdx.x;
    const int sc  = tid & 31;
    const int cg  = tid >> 5;                  // 0..7
    const int g   = rb * 32 + sc;              // chunk-local float4 id
    const int b   = b0 + (g >> 12);            // 4096 float4 per batch plane
    const int sp  = (g & 4095) << 2;           // float offset within plane

    const float* xp = x + (size_t)b * BSTRIDE + sp + (size_t)(cg << 5) * CSTRIDE;

    float4 vmax = make_float4(-INFINITY, -INFINITY, -INFINITY, -INFINITY);
    float4 vsum = make_float4(0.f, 0.f, 0.f, 0.f);

    #pragma unroll 8
    for (int c = 0; c < 32; ++c) {
        const float4 v = *(const float4*)(xp + (size_t)c * CSTRIDE);
        vmax.x = fmaxf(vmax.x, v.x); vmax.y = fmaxf(vmax.y, v.y);
        vmax.z = fmaxf(vmax.z, v.z); vmax.w = fmaxf(vmax.w, v.w);
        vsum.x += v.x; vsum.y += v.y; vsum.z += v.z; vsum.w += v.w;
    }

    smax[tid] = vmax;
    ssum[tid] = vsum;
    __syncthreads();

    if (tid < 32) {
        float4 m = smax[tid];
        float4 s = ssum[tid];
        #pragma unroll
        for (int j = 1; j < 8; ++j) {
            const float4 mj = smax[tid + 32 * j];
            const float4 sj = ssum[tid + 32 * j];
            m.x = fmaxf(m.x, mj.x); m.y = fmaxf(m.y, mj.y);
            m.z = fmaxf(m.z, mj.z); m.w = fmaxf(m.w, mj.w);
            s.x += sj.x; s.y += sj.y; s.z += sj.z; s.w += sj.w;
        }
        const float inv = 1.0f / 256.0f;
        s.x *= inv; s.y *= inv; s.z *= inv; s.w *= inv;
        const int gg = rb * 32 + tid;
        const int bb = b0 + (gg >> 12);
        const int ss = (gg & 4095) << 2;
        *(float4*)(pmax + (size_t)bb * PLANE + ss) = m;
        *(float4*)(pavg + (size_t)bb * PLANE + ss) = s;
    }
}

// ---------------------------------------------------------------------------
// Gate body: 7x7 SAME conv on [max, avg] planes -> hsigmoid gate -> x * gate
// for one (b, h) row (gate block unit gb in [0, CB*128)).
//   Gate phase: 2 threads per pixel, one per plane (49 taps each), LDS-combined.
//   Stream phase: 32 float4-iters/thread, unroll 8, NT stores.
// ---------------------------------------------------------------------------
__device__ __forceinline__ void gate_body(
    const float* __restrict__ x,
    const float* __restrict__ pmax, const float* __restrict__ pavg,
    const float* __restrict__ cw, const float* __restrict__ cb,
    float* __restrict__ out, int b0, int gb)
{
    __shared__ float sw[98];                      // conv_w: [2][7][7]
    __shared__ float part[256];
    __shared__ __align__(16) float sgate[HW];

    const int tid = threadIdx.x;
    if (tid < 98) sw[tid] = cw[tid];
    const int b = b0 + (gb >> 7);
    const int h = gb & 127;
    __syncthreads();

    {
        const int w  = tid & 127;
        const int pl = tid >> 7;                  // 0 = max plane, 1 = avg plane
        const float* pp = (pl ? pavg : pmax) + (size_t)b * PLANE;
        const float* wt = sw + pl * 49;
        float acc = 0.f;
        #pragma unroll
        for (int ky = 0; ky < 7; ++ky) {
            const int hh = h + ky - 3;
            if (hh >= 0 && hh < HW) {
                const float* pr = pp + hh * HW;
                #pragma unroll
                for (int kx = 0; kx < 7; ++kx) {
                    const int ww = w + kx - 3;
                    if (ww >= 0 && ww < HW)
                        acc = fmaf(wt[ky * 7 + kx], pr[ww], acc);
                }
            }
        }
        part[tid] = acc;
    }
    __syncthreads();

    if (tid < HW) {
        const float acc = part[tid] + part[tid + 128] + cb[0];
        // hsigmoid: clip(acc+3, 0, 6) / 6
        sgate[tid] = fminf(fmaxf(acc + 3.0f, 0.0f), 6.0f) * (1.0f / 6.0f);
    }
    __syncthreads();

    const int wc   = tid & 31;   // float4 chunk within the 128-wide row
    const int csub = tid >> 5;   // 0..7 channel phase
    const float4 g4 = *(const float4*)(sgate + wc * 4);
    const size_t rowbase = (size_t)b * BSTRIDE + (size_t)h * HW + wc * 4;

    #pragma unroll 8
    for (int c = csub; c < CHS; c += 8) {
        const size_t off = rowbase + (size_t)c * CSTRIDE;
        const float4 v = *(const float4*)(x + off);
        vf4 r;
        r.x = v.x * g4.x; r.y = v.y * g4.y; r.z = v.z * g4.z; r.w = v.w * g4.w;
        __builtin_nontemporal_store(r, (vf4*)(out + off));
    }
}

// ---------------------------------------------------------------------------
// Stage kernels.
//   reduce_kernel: grid CB*128 = 512 (pipeline head)
//   mid_kernel:    grid 2*CB*128 = 1024; blocks [0,512) gate chunk i-1,
//                  blocks [512,1024) reduce chunk i (true concurrent overlap)
//   gate_kernel:   grid CB*128 = 512 (pipeline tail)
// ---------------------------------------------------------------------------
__global__ __launch_bounds__(256) void reduce_kernel(
    const float* __restrict__ x, float* __restrict__ pmax, float* __restrict__ pavg,
    int b0)
{
    reduce_body(x, pmax, pavg, b0, blockIdx.x);
}

__global__ __launch_bounds__(256) void gate_kernel(
    const float* __restrict__ x,
    const float* __restrict__ pmax, const float* __restrict__ pavg,
    const float* __restrict__ cw, const float* __restrict__ cb,
    float* __restrict__ out, int b0)
{
    gate_body(x, pmax, pavg, cw, cb, out, b0, blockIdx.x);
}

__global__ __launch_bounds__(256) void mid_kernel(
    const float* __restrict__ x, float* __restrict__ pmax, float* __restrict__ pavg,
    const float* __restrict__ cw, const float* __restrict__ cb,
    float* __restrict__ out, int gate_b0, int red_b0)
{
    if (blockIdx.x < CB * 128)
        gate_body(x, pmax, pavg, cw, cb, out, gate_b0, blockIdx.x);
    else
        reduce_body(x, pmax, pavg, red_b0, blockIdx.x - CB * 128);
}

extern "C" void kernel_launch(void* const* d_in, const int* in_sizes, int n_in,
                              void* d_out, int out_size, void* d_ws, size_t ws_size,
                              hipStream_t stream)
{
    const float* x  = (const float*)d_in[0];   // [16,256,128,128] fp32
    const float* cw = (const float*)d_in[1];   // [1,2,7,7] fp32
    const float* cb = (const float*)d_in[2];   // [1] fp32
    float* out = (float*)d_out;

    float* pmax = (float*)d_ws;                        // [16,128,128]
    float* pavg = pmax + (size_t)BATCH * PLANE;        // [16,128,128]

    // Software-pipelined chunks: reduce(c_i+1) overlaps gate/stream(c_i),
    // mixing HBM read and write streams in every middle stage.
    reduce_kernel<<<CB * 128, 256, 0, stream>>>(x, pmax, pavg, 0);
    for (int s = 1; s < NCHUNK; ++s)
        mid_kernel<<<2 * CB * 128, 256, 0, stream>>>(x, pmax, pavg, cw, cb, out,
                                                     (s - 1) * CB, s * CB);
    gate_kernel<<<CB * 128, 256, 0, stream>>>(x, pmax, pavg, cw, cb, out,
                                              (NCHUNK - 1) * CB);
}

// Round 2
// 483.843 us; speedup vs baseline: 1.0103x; 1.0091x over previous
//
#include <hip/hip_runtime.h>
#include <math.h>

// Problem constants (fixed by the reference: B=16, C=256, H=W=128, K=7)
#define HW      128
#define PLANE   16384                 // 128*128
#define CHS     256
#define BATCH   16
#define CSTRIDE 16384                 // plane stride in floats
#define BSTRIDE (256 * 16384)         // batch stride in floats = 4194304

// Two-dispatch layout (diagnosis round): reduce_all then gate_all, full batch.
// Rationale: 5 small dispatches were all invisible under the 164 µs poison
// fills in rocprof top-5; effective BW of the sequence is only ~1.6 TB/s vs
// 6.5 TB/s fill rate and we need per-kernel FETCH/WRITE/dur to see why.
// Both kernels now issue 1 KiB-contiguous wave accesses (64 lanes x float4)
// instead of 2x512B segments, in case DRAM efficiency on scattered 512B
// segments was the hidden cost.

typedef float vf4 __attribute__((ext_vector_type(4)));   // for __builtin_nontemporal_store

// ---------------------------------------------------------------------------
// Kernel 1: channel-wise max + mean over C=256, all 16 batches.
// Grid: 1024 blocks x 256 threads (4 blocks/CU).
//   sc = tid & 63: 64 consecutive float4 -> each wave load is 1 KiB contiguous.
//   cg = tid >> 6: 4 channel groups x 64 channels, combined through LDS.
// ---------------------------------------------------------------------------
__global__ __launch_bounds__(256) void reduce_all(
    const float* __restrict__ x, float* __restrict__ pmax, float* __restrict__ pavg)
{
    __shared__ float4 smax[256];
    __shared__ float4 ssum[256];

    const int tid = threadIdx.x;
    const int sc  = tid & 63;
    const int cg  = tid >> 6;                  // 0..3
    const int g   = blockIdx.x * 64 + sc;      // global float4 id (65536 total)
    const int b   = g >> 12;                   // 4096 float4 per batch plane
    const int sp  = (g & 4095) << 2;           // float offset within plane

    const float* xp = x + (size_t)b * BSTRIDE + sp + (size_t)(cg << 6) * CSTRIDE;

    float4 vmax = make_float4(-INFINITY, -INFINITY, -INFINITY, -INFINITY);
    float4 vsum = make_float4(0.f, 0.f, 0.f, 0.f);

    #pragma unroll 8
    for (int c = 0; c < 64; ++c) {
        const float4 v = *(const float4*)(xp + (size_t)c * CSTRIDE);
        vmax.x = fmaxf(vmax.x, v.x); vmax.y = fmaxf(vmax.y, v.y);
        vmax.z = fmaxf(vmax.z, v.z); vmax.w = fmaxf(vmax.w, v.w);
        vsum.x += v.x; vsum.y += v.y; vsum.z += v.z; vsum.w += v.w;
    }

    smax[tid] = vmax;
    ssum[tid] = vsum;
    __syncthreads();

    if (tid < 64) {
        float4 m = smax[tid];
        float4 s = ssum[tid];
        #pragma unroll
        for (int j = 1; j < 4; ++j) {
            const float4 mj = smax[tid + 64 * j];
            const float4 sj = ssum[tid + 64 * j];
            m.x = fmaxf(m.x, mj.x); m.y = fmaxf(m.y, mj.y);
            m.z = fmaxf(m.z, mj.z); m.w = fmaxf(m.w, mj.w);
            s.x += sj.x; s.y += sj.y; s.z += sj.z; s.w += sj.w;
        }
        const float inv = 1.0f / 256.0f;
        s.x *= inv; s.y *= inv; s.z *= inv; s.w *= inv;
        const int gg = blockIdx.x * 64 + tid;
        const int bb = gg >> 12;
        const int ss = (gg & 4095) << 2;
        *(float4*)(pmax + (size_t)bb * PLANE + ss) = m;
        *(float4*)(pavg + (size_t)bb * PLANE + ss) = s;
    }
}

// ---------------------------------------------------------------------------
// Kernel 2: 7x7 SAME conv on [max, avg] planes -> hsigmoid gate -> x * gate,
// all 16 batches. Grid: 16*64 = 1024 blocks x 256 threads, one block per
// (b, row-pair). Row-pair => per channel the x span is 2 rows = 1 KiB
// contiguous = exactly one wave-wide float4 access.
//   Conv phase: 256 threads = 2 rows x 128 pixels, each thread does both
//   planes (98 taps, planes are L2/L3-resident: 2 MiB total).
//   Stream phase: lane = tid&63 -> float4 within the 1 KiB row-pair span;
//   csub = tid>>6 -> channel phase 0..3; 64 channels/thread, unroll 8,
//   NT stores (write-once output).
// ---------------------------------------------------------------------------
__global__ __launch_bounds__(256) void gate_all(
    const float* __restrict__ x,
    const float* __restrict__ pmax, const float* __restrict__ pavg,
    const float* __restrict__ cw, const float* __restrict__ cb,
    float* __restrict__ out)
{
    __shared__ float sw[98];                      // conv_w: [2][7][7]
    __shared__ __align__(16) float sgate[2][HW];

    const int tid = threadIdx.x;
    if (tid < 98) sw[tid] = cw[tid];
    const int b  = blockIdx.x >> 6;               // 16 batches
    const int hp = blockIdx.x & 63;               // 64 row-pairs
    const int h0 = hp << 1;
    __syncthreads();

    {
        const int w  = tid & 127;
        const int rs = tid >> 7;                  // row within pair: 0 or 1
        const int h  = h0 + rs;
        float acc = cb[0];
        #pragma unroll
        for (int pl = 0; pl < 2; ++pl) {
            const float* pp = (pl ? pavg : pmax) + (size_t)b * PLANE;
            const float* wt = sw + pl * 49;
            #pragma unroll
            for (int ky = 0; ky < 7; ++ky) {
                const int hh = h + ky - 3;
                if (hh >= 0 && hh < HW) {
                    const float* pr = pp + hh * HW;
                    #pragma unroll
                    for (int kx = 0; kx < 7; ++kx) {
                        const int ww = w + kx - 3;
                        if (ww >= 0 && ww < HW)
                            acc = fmaf(wt[ky * 7 + kx], pr[ww], acc);
                    }
                }
            }
        }
        // hsigmoid: clip(acc+3, 0, 6) / 6
        sgate[rs][w] = fminf(fmaxf(acc + 3.0f, 0.0f), 6.0f) * (1.0f / 6.0f);
    }
    __syncthreads();

    const int l    = tid & 63;   // float4 index within the 2-row (1 KiB) span
    const int csub = tid >> 6;   // 0..3 channel phase
    const float4 g4 = *(const float4*)(&sgate[l >> 5][(l & 31) * 4]);
    const size_t spanbase = (size_t)b * BSTRIDE + (size_t)h0 * HW + l * 4;

    #pragma unroll 8
    for (int c = csub; c < CHS; c += 4) {
        const size_t off = spanbase + (size_t)c * CSTRIDE;
        const float4 v = *(const float4*)(x + off);
        vf4 r;
        r.x = v.x * g4.x; r.y = v.y * g4.y; r.z = v.z * g4.z; r.w = v.w * g4.w;
        __builtin_nontemporal_store(r, (vf4*)(out + off));
    }
}

extern "C" void kernel_launch(void* const* d_in, const int* in_sizes, int n_in,
                              void* d_out, int out_size, void* d_ws, size_t ws_size,
                              hipStream_t stream)
{
    const float* x  = (const float*)d_in[0];   // [16,256,128,128] fp32
    const float* cw = (const float*)d_in[1];   // [1,2,7,7] fp32
    const float* cb = (const float*)d_in[2];   // [1] fp32
    float* out = (float*)d_out;

    float* pmax = (float*)d_ws;                        // [16,128,128]
    float* pavg = pmax + (size_t)BATCH * PLANE;        // [16,128,128]

    reduce_all<<<1024, 256, 0, stream>>>(x, pmax, pavg);
    gate_all<<<1024, 256, 0, stream>>>(x, pmax, pavg, cw, cb, out);
}